// Round 3
// baseline (6870.353 us; speedup 1.0000x reference)
//
#include <hip/hip_runtime.h>
#include <hip/hip_bf16.h>

#define N_USERS 100000
#define N_NODES 150000
#define EMB 64
#define RPB 128              // rows per bucket
#define SH 7                 // log2(RPB)
#define NB 1172              // ceil(150000/128)
#define CHUNK 32768

typedef __hip_bfloat16 bf16;

// ---- typed load/store helpers ----
template<typename T> __device__ inline float ldf(const T* p);
template<> __device__ inline float ldf<float>(const float* p) { return *p; }
template<> __device__ inline float ldf<bf16>(const bf16* p) { return __bfloat162float(*p); }
template<typename T> __device__ inline void stf(T* p, float v);
template<> __device__ inline void stf<float>(float* p, float v) { *p = v; }
template<> __device__ inline void stf<bf16>(bf16* p, float v) { *p = __float2bfloat16(v); }

// ---- bucket histogram: LDS-combined then global flush ----
__global__ __launch_bounds__(256)
void bucket_hist(const int* __restrict__ rows, int* __restrict__ bh, int nedges) {
    __shared__ int lh[NB];
    int tid = threadIdx.x;
    for (int i = tid; i < NB; i += 256) lh[i] = 0;
    __syncthreads();
    int stride = gridDim.x * blockDim.x;
    for (int e = blockIdx.x * blockDim.x + tid; e < nedges; e += stride)
        atomicAdd(&lh[rows[e] >> SH], 1);
    __syncthreads();
    for (int b = tid; b < NB; b += 256) {
        int h = lh[b];
        if (h) atomicAdd(&bh[b], h);
    }
}

// ---- single-block exclusive scan of NB bucket counts ----
__global__ __launch_bounds__(1024)
void scan_single(const int* __restrict__ bh, int* __restrict__ base,
                 int* __restrict__ cursor, int nedges) {
    __shared__ int wsum[16];
    __shared__ int carry;
    int tid = threadIdx.x, lane = tid & 63, wid = tid >> 6;
    if (tid == 0) carry = 0;
    __syncthreads();
    for (int t0 = 0; t0 < NB; t0 += 1024) {
        int i = t0 + tid;
        int v = (i < NB) ? bh[i] : 0;
        int s = v;
        #pragma unroll
        for (int d = 1; d < 64; d <<= 1) { int t = __shfl_up(s, d); if (lane >= d) s += t; }
        if (lane == 63) wsum[wid] = s;
        __syncthreads();
        if (wid == 0 && lane < 16) {
            int w = wsum[lane];
            #pragma unroll
            for (int d = 1; d < 16; d <<= 1) { int t = __shfl_up(w, d); if (lane >= d) w += t; }
            wsum[lane] = w;
        }
        __syncthreads();
        int excl = (wid ? wsum[wid - 1] : 0) + (s - v) + carry;
        if (i < NB) { base[i] = excl; cursor[i] = excl; }
        __syncthreads();
        if (tid == 1023) carry += wsum[15];
        __syncthreads();
    }
    if (tid == 0) base[NB] = nedges;
}

// ---- chunked scatter into bucket-grouped records (coalesced runs) ----
__global__ __launch_bounds__(512)
void bucket_scatter(const int* __restrict__ rows, const int* __restrict__ cols,
                    const float* __restrict__ vals, int* __restrict__ cursor,
                    int2* __restrict__ rec, int nedges) {
    __shared__ int lh[NB], gb[NB], lc[NB];
    int tid = threadIdx.x;
    int cs = blockIdx.x * CHUNK;
    int cn = min(CHUNK, nedges - cs);
    for (int i = tid; i < NB; i += 512) { lh[i] = 0; lc[i] = 0; }
    __syncthreads();
    for (int i = tid; i < cn; i += 512)
        atomicAdd(&lh[rows[cs + i] >> SH], 1);
    __syncthreads();
    for (int b = tid; b < NB; b += 512) {
        int h = lh[b];
        if (h) gb[b] = atomicAdd(&cursor[b], h);
    }
    __syncthreads();
    for (int i = tid; i < cn; i += 512) {
        int e = cs + i;
        int r = rows[e];
        int b = r >> SH;
        int p = atomicAdd(&lc[b], 1);
        rec[gb[b] + p] = make_int2(((r & (RPB - 1)) << 18) | cols[e],
                                   __float_as_int(vals[e]));
    }
}

// ---- SpMM: one block per bucket, 32 KB LDS f32 accumulator ----
template<typename XT, typename YT>
__global__ __launch_bounds__(512)
void spmm_bucket(const int2* __restrict__ rec, const int* __restrict__ base,
                 const XT* __restrict__ xu, const XT* __restrict__ xi,
                 YT* __restrict__ y) {
    __shared__ float acc[RPB * EMB];   // 32 KB
    int b = blockIdx.x;
    int tid = threadIdx.x, lane = tid & 63, wave = tid >> 6;
    for (int i = tid; i < RPB * EMB; i += 512) acc[i] = 0.f;
    __syncthreads();
    int s = base[b], e = base[b + 1];
    int k = s + wave;
    for (; k + 8 < e; k += 16) {
        int2 r0 = rec[k], r1 = rec[k + 8];
        unsigned p0 = (unsigned)r0.x, p1 = (unsigned)r1.x;
        int c0 = p0 & 0x3FFFF, c1 = p1 & 0x3FFFF;
        int rl0 = p0 >> 18, rl1 = p1 >> 18;
        float v0 = __int_as_float(r0.y), v1 = __int_as_float(r1.y);
        const XT* s0 = (c0 < N_USERS) ? xu + (size_t)c0 * EMB : xi + (size_t)(c0 - N_USERS) * EMB;
        const XT* s1 = (c1 < N_USERS) ? xu + (size_t)c1 * EMB : xi + (size_t)(c1 - N_USERS) * EMB;
        float x0 = ldf(s0 + lane);
        float x1 = ldf(s1 + lane);
        atomicAdd(&acc[rl0 * EMB + lane], v0 * x0);
        atomicAdd(&acc[rl1 * EMB + lane], v1 * x1);
    }
    for (; k < e; k += 8) {
        int2 r0 = rec[k];
        unsigned p0 = (unsigned)r0.x;
        int c0 = p0 & 0x3FFFF;
        int rl0 = p0 >> 18;
        float v0 = __int_as_float(r0.y);
        const XT* s0 = (c0 < N_USERS) ? xu + (size_t)c0 * EMB : xi + (size_t)(c0 - N_USERS) * EMB;
        atomicAdd(&acc[rl0 * EMB + lane], v0 * ldf(s0 + lane));
    }
    __syncthreads();
    int rowbase = b * RPB;
    int nrows = min(RPB, N_NODES - rowbase);
    for (int j = wave; j < nrows; j += 8)
        stf(&y[(size_t)(rowbase + j) * EMB + lane], acc[j * EMB + lane]);
}

// ---- batch-row output kernels ----
__global__ void out_init(const int* __restrict__ user, const int* __restrict__ item,
                         const float* __restrict__ ue, const float* __restrict__ ie,
                         float* __restrict__ out, int batch) {
    int wave = (blockIdx.x * blockDim.x + threadIdx.x) >> 6;
    int lane = threadIdx.x & 63;
    if (wave < batch)
        out[(size_t)wave * EMB + lane] = ue[(size_t)user[wave] * EMB + lane];
    else if (wave < 2 * batch)
        out[(size_t)wave * EMB + lane] = ie[(size_t)item[wave - batch] * EMB + lane];
}

template<typename HT>
__global__ void out_add(const int* __restrict__ user, const int* __restrict__ item,
                        const HT* __restrict__ h, float* __restrict__ out,
                        int batch, float scale) {
    int wave = (blockIdx.x * blockDim.x + threadIdx.x) >> 6;
    int lane = threadIdx.x & 63;
    if (wave < 2 * batch) {
        int node = (wave < batch) ? user[wave] : (N_USERS + item[wave - batch]);
        size_t o = (size_t)wave * EMB + lane;
        out[o] = (out[o] + ldf(&h[(size_t)node * EMB + lane])) * scale;
    }
}

// ---- pipeline (templated on h-storage type) ----
template<typename HT>
static void run_pipeline(const int* user, const int* item, const int* rows,
                         const int* cols, const float* vals,
                         const float* ue, const float* ie, float* out,
                         int2* rec, int* bh, int* base, int* cursor, HT* hA, HT* hB,
                         int nedges, int batch, hipStream_t stream) {
    hipMemsetAsync(bh, 0, NB * sizeof(int), stream);
    bucket_hist<<<1024, 256, 0, stream>>>(rows, bh, nedges);
    scan_single<<<1, 1024, 0, stream>>>(bh, base, cursor, nedges);
    bucket_scatter<<<(nedges + CHUNK - 1) / CHUNK, 512, 0, stream>>>(
        rows, cols, vals, cursor, rec, nedges);

    const int oblocks = (2 * batch * 64) / 256;
    out_init<<<oblocks, 256, 0, stream>>>(user, item, ue, ie, out, batch);

    // layer 1: x = (ue, ie) f32
    spmm_bucket<float, HT><<<NB, 512, 0, stream>>>(rec, base, ue, ie, hA);
    out_add<HT><<<oblocks, 256, 0, stream>>>(user, item, hA, out, batch, 1.0f);
    // layer 2: x = hA
    spmm_bucket<HT, HT><<<NB, 512, 0, stream>>>(rec, base, hA, hA + (size_t)N_USERS * EMB, hB);
    out_add<HT><<<oblocks, 256, 0, stream>>>(user, item, hB, out, batch, 1.0f);
    // layer 3: x = hB, reuse hA
    spmm_bucket<HT, HT><<<NB, 512, 0, stream>>>(rec, base, hB, hB + (size_t)N_USERS * EMB, hA);
    out_add<HT><<<oblocks, 256, 0, stream>>>(user, item, hA, out, batch, 0.25f);
}

extern "C" void kernel_launch(void* const* d_in, const int* in_sizes, int n_in,
                              void* d_out, int out_size, void* d_ws, size_t ws_size,
                              hipStream_t stream) {
    const int*   user = (const int*)d_in[0];
    const int*   item = (const int*)d_in[1];
    const int*   rows = (const int*)d_in[2];
    const int*   cols = (const int*)d_in[3];
    const float* vals = (const float*)d_in[4];
    const float* ue   = (const float*)d_in[5];
    const float* ie   = (const float*)d_in[6];
    float*       out  = (float*)d_out;

    const int nedges = in_sizes[2];
    const int batch  = in_sizes[0];

    char* p = (char*)d_ws;
    int2* rec    = (int2*)p;  p += (size_t)nedges * sizeof(int2);   // 51.2 MB
    int*  bh     = (int*)p;   p += 8192;
    int*  base   = (int*)p;   p += 8192;                            // NB+1 ints
    int*  cursor = (int*)p;   p += 8192;

    const size_t hFloats = (size_t)N_NODES * EMB;
    const size_t headBytes = (size_t)(p - (char*)d_ws);

    if (ws_size >= headBytes + 2 * hFloats * sizeof(float)) {
        float* hA = (float*)p;
        float* hB = hA + hFloats;
        run_pipeline<float>(user, item, rows, cols, vals, ue, ie, out,
                            rec, bh, base, cursor, hA, hB, nedges, batch, stream);
    } else {
        bf16* hA = (bf16*)p;
        bf16* hB = hA + hFloats;
        run_pipeline<bf16>(user, item, rows, cols, vals, ue, ie, out,
                           rec, bh, base, cursor, hA, hB, nedges, batch, stream);
    }
}